// Round 2
// baseline (72.119 us; speedup 1.0000x reference)
//
#include <hip/hip_runtime.h>

// UFLAttention collapses: softmax over the contracted key axis sums to 1,
// so combined[b,i] = (x[b,i]*sum_h(Wv[i,h]) + sum_h(bv[i,h])) / sqrt(D).
// Then y = relu(x + combined), out = layernorm(y)*gamma + beta.
// Wq/bq/Wk/bk are never read.
//
// v2 (resubmit — round-1 bench failed on container acquisition, no data):
// one WAVE per batch row (lane handles 4 features via float4):
//   - no LDS, no __syncthreads (wave-local butterfly reduction)
//   - all global loads/stores are float4 (16 B/lane)
//   - 4 rows per 256-thread block -> grid = 128 blocks
// This is a probe as much as an optimization: kernel-side work is strictly
// reduced vs v1; if dur_us doesn't move, the bench time is harness-fill-bound.

constexpr int B_DIM = 512;
constexpr int D_DIM = 256;
constexpr int ROWS_PER_BLOCK = 4;

__global__ __launch_bounds__(256) void ufl_collapsed_v2(
    const float* __restrict__ x,      // [B, D]
    const float* __restrict__ Wv,     // [D, H] (H=8)
    const float* __restrict__ bv,     // [D, H]
    const float* __restrict__ gamma,  // [D]
    const float* __restrict__ beta,   // [D]
    float* __restrict__ out)          // [B, D]
{
    const int wave = threadIdx.x >> 6;                 // 0..3
    const int lane = threadIdx.x & 63;                 // 0..63
    const int b    = blockIdx.x * ROWS_PER_BLOCK + wave;
    const int f0   = lane * 4;                         // first of 4 features

    const float4 xv = *reinterpret_cast<const float4*>(x + b * D_DIM + f0);
    const float xs[4] = {xv.x, xv.y, xv.z, xv.w};

    // Wv/bv rows are 8 contiguous floats = 2x float4; tiny (8 KB), L1/L2-cached.
    const float4* __restrict__ Wv4 = reinterpret_cast<const float4*>(Wv);
    const float4* __restrict__ bv4 = reinterpret_cast<const float4*>(bv);

    float y[4];
    float s = 0.0f, ss = 0.0f;
#pragma unroll
    for (int j = 0; j < 4; ++j) {
        const int f = f0 + j;
        const float4 w0 = Wv4[f * 2 + 0];
        const float4 w1 = Wv4[f * 2 + 1];
        const float4 c0 = bv4[f * 2 + 0];
        const float4 c1 = bv4[f * 2 + 1];
        const float svw = ((w0.x + w0.y) + (w0.z + w0.w))
                        + ((w1.x + w1.y) + (w1.z + w1.w));
        const float svb = ((c0.x + c0.y) + (c0.z + c0.w))
                        + ((c1.x + c1.y) + (c1.z + c1.w));
        // combined = v_rowsum / sqrt(D); sqrt(256) = 16
        const float combined = (xs[j] * svw + svb) * 0.0625f;
        const float yy = fmaxf(xs[j] + combined, 0.0f);
        y[j] = yy;
        s  += yy;
        ss += yy * yy;
    }

    // Wave-wide butterfly reduction over 64 lanes (every lane gets the total).
#pragma unroll
    for (int off = 32; off >= 1; off >>= 1) {
        s  += __shfl_xor(s,  off, 64);
        ss += __shfl_xor(ss, off, 64);
    }

    const float mu  = s  * (1.0f / D_DIM);
    const float var = ss * (1.0f / D_DIM) - mu * mu;
    const float inv = 1.0f / sqrtf(var + 1e-5f);

    const float4 g4 = *reinterpret_cast<const float4*>(gamma + f0);
    const float4 b4 = *reinterpret_cast<const float4*>(beta  + f0);

    float4 o;
    o.x = (y[0] - mu) * inv * g4.x + b4.x;
    o.y = (y[1] - mu) * inv * g4.y + b4.y;
    o.z = (y[2] - mu) * inv * g4.z + b4.z;
    o.w = (y[3] - mu) * inv * g4.w + b4.w;
    *reinterpret_cast<float4*>(out + b * D_DIM + f0) = o;
}

extern "C" void kernel_launch(void* const* d_in, const int* in_sizes, int n_in,
                              void* d_out, int out_size, void* d_ws, size_t ws_size,
                              hipStream_t stream) {
    // setup_inputs order: x, Wq, bq, Wk, bk, Wv, bv, gamma, beta
    const float* x     = (const float*)d_in[0];
    const float* Wv    = (const float*)d_in[5];
    const float* bv    = (const float*)d_in[6];
    const float* gamma = (const float*)d_in[7];
    const float* beta  = (const float*)d_in[8];
    float* out = (float*)d_out;

    ufl_collapsed_v2<<<B_DIM / ROWS_PER_BLOCK, 256, 0, stream>>>(
        x, Wv, bv, gamma, beta, out);
}